// Round 2
// baseline (102.671 us; speedup 1.0000x reference)
//
#include <hip/hip_runtime.h>
#include <hip/hip_bf16.h>

#define Tt 512
#define Bb 512
#define DV 256
#define DQ 128
#define DH 64
#define CTXN (Tt * DV)  // 131072 floats: context part of d_out

typedef __attribute__((ext_vector_type(8))) short bf16x8;
typedef __attribute__((ext_vector_type(4))) float f32x4;

__device__ __forceinline__ unsigned short f2bf(float x) {
  unsigned u = __float_as_uint(x);
  u += 0x7FFFu + ((u >> 16) & 1u);   // RNE
  return (unsigned short)(u >> 16);
}

// ---- Kernel 0a: qh[b,h] = sum_q W2[h,q]*query[b,q] + b2[h] + b1[h] ----
__global__ void qh_kernel(const float* __restrict__ query,
                          const float* __restrict__ W2,
                          const float* __restrict__ b1,
                          const float* __restrict__ b2,
                          float* __restrict__ qh) {
  int b = blockIdx.x;      // 512
  int h = threadIdx.x;     // 64
  __shared__ float q[DQ];
  q[h]      = query[b * DQ + h];
  q[h + 64] = query[b * DQ + h + 64];
  __syncthreads();
  const float* w2r = W2 + h * DQ;
  float acc = 0.f;
#pragma unroll 8
  for (int k = 0; k < DQ; ++k) acc = fmaf(w2r[k], q[k], acc);
  qh[b * DH + h] = acc + b1[h] + b2[h];
}

// ---- Kernel 0b: W1 f32 -> bf16 ----
__global__ void w1_cvt_kernel(const float* __restrict__ W1,
                              unsigned short* __restrict__ w1bf) {
  int i = blockIdx.x * 256 + threadIdx.x;  // grid 64 -> 16384
  w1bf[i] = f2bf(W1[i]);
}

// ---- Kernel 1: scores. Block = 64 rows of [B*T, 256] @ W1^T -> tanh -> Wv dot ----
// sT[t*512 + b] = score
__global__ __launch_bounds__(256, 2) void score_kernel(
    const float* __restrict__ values,
    const unsigned short* __restrict__ w1bf,
    const float* __restrict__ qh,
    const float* __restrict__ Wv,
    const float* __restrict__ bv,
    float* __restrict__ sT) {
  __shared__ __align__(16) unsigned short lA[64 * DV];  // 32 KB, swizzled bf16
  __shared__ __align__(16) unsigned short lB[DH * DV];  // 32 KB, swizzled bf16
  const int tid = threadIdx.x;
  const int m0 = blockIdx.x * 64;
  const int bidx = m0 >> 9;  // all 64 rows share the same b (64 | 512)

  // stage W1 bf16 -> lB (16B units), XOR-swizzle byte ^= (row&7)<<4
  const uint4* w1v = (const uint4*)w1bf;
#pragma unroll
  for (int i = 0; i < 8; ++i) {
    int vec = i * 256 + tid;        // 2048 units of 16B
    uint4 d = w1v[vec];
    int row = vec >> 5;             // 32 units per 256-elem row
    int u = vec & 31;
    int byte = (row << 9) + (u << 4);
    *(uint4*)((char*)lB + (byte ^ ((row & 7) << 4))) = d;
  }
  // stage values rows m0..m0+63: f32 -> bf16, 8B units, same swizzle
  const float4* vg = (const float4*)values + m0 * (DV / 4);
#pragma unroll
  for (int i = 0; i < 16; ++i) {
    int vec = i * 256 + tid;        // 4096 float4 units
    float4 d = vg[vec];
    int row = vec >> 6;             // 64 float4 per row
    int c4 = vec & 63;
    uint2 p;
    p.x = (unsigned)f2bf(d.x) | ((unsigned)f2bf(d.y) << 16);
    p.y = (unsigned)f2bf(d.z) | ((unsigned)f2bf(d.w) << 16);
    int byte = (row << 9) + (c4 << 3);
    *(uint2*)((char*)lA + (byte ^ ((row & 7) << 4))) = p;
  }
  __syncthreads();

  const int wv = tid >> 6;        // wave 0..3 -> rows 16*wv .. +15
  const int lane = tid & 63;
  const int lrow = lane & 15;
  const int g = lane >> 4;        // k-group

  f32x4 acc[4];
#pragma unroll
  for (int nt = 0; nt < 4; ++nt) acc[nt] = (f32x4){0.f, 0.f, 0.f, 0.f};

  const int arow = wv * 16 + lrow;
#pragma unroll
  for (int ks = 0; ks < 8; ++ks) {
    int k2 = (ks * 32 + g * 8) * 2;  // byte offset of k within row
    // full byte offset FIRST, then swizzle-XOR (must match write side exactly)
    int abyte = ((arow << 9) + k2) ^ ((arow & 7) << 4);
    bf16x8 af = *(const bf16x8*)((const char*)lA + abyte);
#pragma unroll
    for (int nt = 0; nt < 4; ++nt) {
      int brow = nt * 16 + lrow;
      bf16x8 bf = *(const bf16x8*)((const char*)lB +
                                   (((brow << 9) + k2) ^ ((brow & 7) << 4)));
      acc[nt] = __builtin_amdgcn_mfma_f32_16x16x32_bf16(af, bf, acc[nt], 0, 0, 0);
    }
  }

  // epilogue: h + qh -> tanh -> * Wv, reduce over 64 cols
  float bv0 = bv[0];
  float sc[4] = {0.f, 0.f, 0.f, 0.f};
#pragma unroll
  for (int nt = 0; nt < 4; ++nt) {
    int col = nt * 16 + lrow;
    float qv = qh[bidx * DH + col];
    float wvc = Wv[col];
#pragma unroll
    for (int j = 0; j < 4; ++j) {
      float hv = acc[nt][j] + qv;
      float e = __expf(2.f * hv);
      float th = (e - 1.f) / (e + 1.f);
      sc[j] = fmaf(th, wvc, sc[j]);
    }
  }
#pragma unroll
  for (int j = 0; j < 4; ++j) {
    float v = sc[j];
    v += __shfl_xor(v, 1);
    v += __shfl_xor(v, 2);
    v += __shfl_xor(v, 4);
    v += __shfl_xor(v, 8);
    sc[j] = v;
  }
  if (lrow == 0) {
#pragma unroll
    for (int j = 0; j < 4; ++j) {
      int m = m0 + wv * 16 + g * 4 + j;
      int tt = m & (Tt - 1);
      sT[tt * Bb + bidx] = sc[j] + bv0;
    }
  }
}

// ---- Kernel 2: per-t softmax over b + weighted context reduction ----
__global__ __launch_bounds__(256) void ctx_kernel(
    const float* __restrict__ values,
    const float* __restrict__ sT,
    float* __restrict__ out) {
  const int t = blockIdx.x;
  const int tid = threadIdx.x;
  const int wv = tid >> 6, lane = tid & 63;
  __shared__ float wbuf[Bb];
  __shared__ float smax[4], ssum[4];
  __shared__ float4 cred[3][64];

  float s0 = sT[t * Bb + tid];
  float s1 = sT[t * Bb + tid + 256];
  float mx = fmaxf(s0, s1);
#pragma unroll
  for (int d = 1; d < 64; d <<= 1) mx = fmaxf(mx, __shfl_xor(mx, d));
  if (lane == 0) smax[wv] = mx;
  __syncthreads();
  mx = fmaxf(fmaxf(smax[0], smax[1]), fmaxf(smax[2], smax[3]));
  float w0 = __expf(s0 - mx), w1 = __expf(s1 - mx);
  float zs = w0 + w1;
#pragma unroll
  for (int d = 1; d < 64; d <<= 1) zs += __shfl_xor(zs, d);
  if (lane == 0) ssum[wv] = zs;
  __syncthreads();
  float invZ = 1.f / (ssum[0] + ssum[1] + ssum[2] + ssum[3]);
  float wn0 = w0 * invZ, wn1 = w1 * invZ;
  wbuf[tid] = wn0;
  wbuf[tid + 256] = wn1;
  out[CTXN + tid * Tt + t] = wn0;          // attention_weights[b,t]
  out[CTXN + (tid + 256) * Tt + t] = wn1;
  __syncthreads();

  // context[t,:] = sum_b w[b] * values[b,t,:]; wave wv owns b = wv (mod 4)
  const float4* vp = (const float4*)values;
  float4 acc = make_float4(0.f, 0.f, 0.f, 0.f);
#pragma unroll 4
  for (int b = wv; b < Bb; b += 4) {
    float4 v = vp[(size_t)(b * Tt + t) * (DV / 4) + lane];
    float w = wbuf[b];
    acc.x = fmaf(w, v.x, acc.x);
    acc.y = fmaf(w, v.y, acc.y);
    acc.z = fmaf(w, v.z, acc.z);
    acc.w = fmaf(w, v.w, acc.w);
  }
  if (wv > 0) cred[wv - 1][lane] = acc;
  __syncthreads();
  if (wv == 0) {
    float4 a1 = cred[0][lane], a2 = cred[1][lane], a3 = cred[2][lane];
    acc.x += a1.x + a2.x + a3.x;
    acc.y += a1.y + a2.y + a3.y;
    acc.z += a1.z + a2.z + a3.z;
    acc.w += a1.w + a2.w + a3.w;
    ((float4*)out)[t * (DV / 4) + lane] = acc;
  }
}

extern "C" void kernel_launch(void* const* d_in, const int* in_sizes, int n_in,
                              void* d_out, int out_size, void* d_ws, size_t ws_size,
                              hipStream_t stream) {
  const float* query  = (const float*)d_in[0];
  const float* values = (const float*)d_in[1];
  const float* W1     = (const float*)d_in[2];
  const float* b1     = (const float*)d_in[3];
  const float* W2     = (const float*)d_in[4];
  const float* b2     = (const float*)d_in[5];
  const float* Wv     = (const float*)d_in[6];
  const float* bv     = (const float*)d_in[7];
  float* out = (float*)d_out;
  char* ws = (char*)d_ws;
  float* qh            = (float*)ws;                      // 512*64*4   = 128 KB
  unsigned short* w1bf = (unsigned short*)(ws + 131072);  // 16384*2    =  32 KB
  float* sT            = (float*)(ws + 131072 + 32768);   // 512*512*4  =   1 MB

  hipLaunchKernelGGL(qh_kernel, dim3(Bb), dim3(DH), 0, stream, query, W2, b1, b2, qh);
  hipLaunchKernelGGL(w1_cvt_kernel, dim3(64), dim3(256), 0, stream, W1, w1bf);
  hipLaunchKernelGGL(score_kernel, dim3((Bb * Tt) / 64), dim3(256), 0, stream,
                     values, w1bf, qh, Wv, bv, sT);
  hipLaunchKernelGGL(ctx_kernel, dim3(Tt), dim3(256), 0, stream, values, sT, out);
}